// Round 9
// baseline (202.177 us; speedup 1.0000x reference)
//
#include <hip/hip_runtime.h>
#include <hip/hip_bf16.h>
#include <cstdint>

typedef _Float16 f16;
typedef _Float16 f16x4 __attribute__((ext_vector_type(4)));
typedef _Float16 f16x8 __attribute__((ext_vector_type(8)));
typedef float f32x4 __attribute__((ext_vector_type(4)));

#define MFMA16(a, b, c) __builtin_amdgcn_mfma_f32_16x16x32_f16((a), (b), (c), 0, 0, 0)

constexpr int BATCH = 16;
constexpr int C     = 256;    // dim
constexpr int HW    = 4096;   // 64*64 spatial
constexpr int DH    = 32;     // qkv_dim
constexpr float EPS = 1e-5f;

// ---- workspace layout (bytes) ----
constexpr size_t OFF_XT = 0;                                   // XTF frag-major f16 [16][64tile][16KB]
constexpr size_t SZ_XT  = (size_t)BATCH * HW * C * 2;          // 32 MB
constexpr size_t OFF_W1 = OFF_XT + SZ_XT;                      // WqF (131072 B) + WkvF (16384 B)
constexpr size_t OFF_B1 = OFF_W1 + 147456;                     // f32 [288]
constexpr size_t OFF_WP = OFF_B1 + 2048;                       // WpF frag-major
constexpr size_t SZ_WP  = (size_t)C * C * 2;
constexpr size_t OFF_BP = OFF_WP + SZ_WP;                      // f32 [256]
constexpr size_t OFF_U  = OFF_BP + 1024;                       // f32 [16][32][32] (unnormalized ctx)
constexpr size_t OFF_S  = OFF_U + 65536;                       // f32 [16][32] spatial exp-sums

__device__ __forceinline__ f16x8 ld8(const f16* p) {           // 8B-aligned LDS load
  f16x4 lo = *(const f16x4*)p;
  f16x4 hi = *(const f16x4*)(p + 4);
  return __builtin_shufflevector(lo, hi, 0, 1, 2, 3, 4, 5, 6, 7);
}

// ============================================================================
// K0: fold BN into conv weights (FRAGMENT-MAJOR f16) + zero U/S accumulators.
// Frag layout: idx = ((kc*NT + ot)*64 + lane)*8 + j holds
//   W[o = ot*16 + (lane&15)][c = kc*32 + (lane>>4)*8 + j]
// ============================================================================
__global__ __launch_bounds__(256) void k0_prep(
    const float* __restrict__ Wq,  const float* __restrict__ gq,  const float* __restrict__ bq,
    const float* __restrict__ mq,  const float* __restrict__ vq,
    const float* __restrict__ Wkv, const float* __restrict__ gkv, const float* __restrict__ bkv,
    const float* __restrict__ mkv, const float* __restrict__ vkv,
    const float* __restrict__ Wp,  const float* __restrict__ gp,  const float* __restrict__ bp,
    const float* __restrict__ mp,  const float* __restrict__ vp,
    f16* __restrict__ WqF, float* __restrict__ b1, f16* __restrict__ WpF,
    float* __restrict__ bp2, f16* __restrict__ WkvF, float* __restrict__ U,
    float* __restrict__ S) {
  int id = blockIdx.x * 256 + threadIdx.x;
  if (id < 65536) {
    int j = id & 7, lane = (id >> 3) & 63, ot = (id >> 9) & 15, kc = id >> 13;
    int o = ot * 16 + (lane & 15), c = kc * 32 + ((lane >> 4) << 3) + j;
    float inv = gq[o] * rsqrtf(vq[o] + EPS);
    WqF[id] = (f16)(Wq[o * 256 + c] * inv);
  } else if (id < 131072) {
    int id2 = id - 65536;
    int j = id2 & 7, lane = (id2 >> 3) & 63, ot = (id2 >> 9) & 15, kc = id2 >> 13;
    int o = ot * 16 + (lane & 15), c = kc * 32 + ((lane >> 4) << 3) + j;
    float inv = gp[o] * rsqrtf(vp[o] + EPS);
    WpF[id2] = (f16)(Wp[o * 256 + c] * inv);
  } else if (id < 139264) {
    int id2 = id - 131072;
    int j = id2 & 7, lane = (id2 >> 3) & 63, ot = (id2 >> 9) & 1, kc = id2 >> 10;
    int o = ot * 16 + (lane & 15), c = kc * 32 + ((lane >> 4) << 3) + j;
    float inv = gkv[o] * rsqrtf(vkv[o] + EPS);
    WkvF[id2] = (f16)(Wkv[o * 256 + c] * inv);
  } else if (id < 139552) {
    int r = id - 139264;
    if (r < 256) { float inv = gq[r] * rsqrtf(vq[r] + EPS);   b1[r] = bq[r] - mq[r] * inv; }
    else { int e = r - 256; float inv = gkv[e] * rsqrtf(vkv[e] + EPS); b1[r] = bkv[e] - mkv[e] * inv; }
  } else if (id < 139808) {
    int o = id - 139552;
    float inv = gp[o] * rsqrtf(vp[o] + EPS);
    bp2[o] = bp[o] - mp[o] * inv;
  } else if (id < 156192) {
    U[id - 139808] = 0.f;
  } else if (id < 156704) {
    S[id - 156192] = 0.f;
  }
}

// ============================================================================
// KA: per 64-position tile (no q-GEMM -> small register footprint, (256,4)):
//   ph1: ALL 16 X-loads batched into registers (max memory-level parallelism),
//        then 4x4 register transpose f32->f16 -> xt LDS [n][c]
//   ph2: XTF frag-major stores + kv-GEMM (WkvF frag-major, L1-hot)
//   ph3: kv accs -> kvb LDS (aliases xt, pitch 65 conflict-free)
//   ph4: partial ctx U[d][e] += kv.exp(kv)^T via MFMA + atomics;
//        S[e] += sum exp(kv)  (kv bounded so exp is max-free)
// ============================================================================
__global__ __launch_bounds__(256, 4) void ka_trans_kv(
    const float* __restrict__ X, const f16* __restrict__ WkvF, const float* __restrict__ bkv1,
    f16* __restrict__ XTF, float* __restrict__ U, float* __restrict__ S) {
  __shared__ alignas(16) f16 xt[64 * 260];     // [n][c] pitch 260; reused as kvb
  float* kvb = (float*)xt;                     // [d][n] pitch 65 (8320 B)
  const int t = threadIdx.x, b = blockIdx.y, n0 = blockIdx.x * 64;
  const int lane = t & 63, w = t >> 6, l15 = lane & 15, quad = lane >> 4;
  const int wn = w & 1, wm = w >> 1;
  const float* Xb = X + (size_t)b * C * HW;

  // ph1: batch-issue all 16 global loads, then transpose f32->f16 into LDS
  {
    int n4 = (t & 15) * 4, c4 = (t >> 4) * 4;
    float4 vb[4][4];
#pragma unroll
    for (int ci = 0; ci < 4; ++ci) {
      const float* xp = Xb + (size_t)(ci * 64 + c4) * HW + n0 + n4;
      vb[ci][0] = *(const float4*)&xp[0];
      vb[ci][1] = *(const float4*)&xp[HW];
      vb[ci][2] = *(const float4*)&xp[2 * HW];
      vb[ci][3] = *(const float4*)&xp[3 * HW];
    }
#pragma unroll
    for (int ci = 0; ci < 4; ++ci) {
      int c0 = ci * 64 + c4;
      float4 v0 = vb[ci][0], v1 = vb[ci][1], v2 = vb[ci][2], v3 = vb[ci][3];
      f16x4 w0 = {(f16)v0.x, (f16)v1.x, (f16)v2.x, (f16)v3.x};
      f16x4 w1 = {(f16)v0.y, (f16)v1.y, (f16)v2.y, (f16)v3.y};
      f16x4 w2 = {(f16)v0.z, (f16)v1.z, (f16)v2.z, (f16)v3.z};
      f16x4 w3 = {(f16)v0.w, (f16)v1.w, (f16)v2.w, (f16)v3.w};
      *(f16x4*)&xt[(n4 + 0) * 260 + c0] = w0;
      *(f16x4*)&xt[(n4 + 1) * 260 + c0] = w1;
      *(f16x4*)&xt[(n4 + 2) * 260 + c0] = w2;
      *(f16x4*)&xt[(n4 + 3) * 260 + c0] = w3;
    }
  }
  __syncthreads();   // sync A

  // ph2a: XTF fragment-major stores (consecutive 16B per thread, coalesced)
  {
    f16* XFt = XTF + ((size_t)b * 64 + blockIdx.x) * 16384;
#pragma unroll
    for (int i = 0; i < 8; ++i) {
      int u = t + i * 256;                     // (kc,nt,lane) linear
      int l15u = u & 15, qdu = (u >> 4) & 3, ntu = (u >> 6) & 3, kcu = u >> 8;
      f16x8 v = ld8(&xt[(ntu * 16 + l15u) * 260 + kcu * 32 + qdu * 8]);
      *(f16x8*)&XFt[(size_t)u * 8] = v;
    }
  }

  // ph2b: kv GEMM. A = xt rows (wave w owns n rows w*16..+15),
  // B-frags frag-major from WkvF (16KB, L1-hot). Bias in acc init.
  f32x4 acc0, acc1;
  {
    float bv0 = bkv1[l15], bv1 = bkv1[16 + l15];
#pragma unroll
    for (int r = 0; r < 4; ++r) { acc0[r] = bv0; acc1[r] = bv1; }
  }
#pragma unroll
  for (int kc = 0; kc < 8; ++kc) {
    f16x8 af  = ld8(&xt[(w * 16 + l15) * 260 + kc * 32 + quad * 8]);
    f16x8 bf0 = *(const f16x8*)&WkvF[((size_t)(kc * 2 + 0) * 64 + lane) * 8];
    f16x8 bf1 = *(const f16x8*)&WkvF[((size_t)(kc * 2 + 1) * 64 + lane) * 8];
    acc0 = MFMA16(af, bf0, acc0);
    acc1 = MFMA16(af, bf1, acc1);
  }
  __syncthreads();   // sync B: all xt reads done -> safe to alias as kvb

  // ph3: kv accs -> kvb [d][n] pitch 65
#pragma unroll
  for (int r = 0; r < 4; ++r) {
    int n = w * 16 + quad * 4 + r;
    kvb[l15 * 65 + n] = acc0[r];
    kvb[(16 + l15) * 65 + n] = acc1[r];
  }
  __syncthreads();   // sync C

  // ph4a: partial ctx via MFMA; wave -> quadrant (dh=wn, eh=wm)
  {
    f32x4 cx = {0.f, 0.f, 0.f, 0.f};
#pragma unroll
    for (int ks = 0; ks < 2; ++ks) {
      f16x8 A, B;
#pragma unroll
      for (int j = 0; j < 8; ++j) {
        float av = kvb[(wn * 16 + l15) * 65 + ks * 32 + quad * 8 + j];
        float bv = kvb[(wm * 16 + l15) * 65 + ks * 32 + quad * 8 + j];
        A[j] = (f16)av;
        B[j] = (f16)__expf(bv);
      }
      cx = MFMA16(A, B, cx);
    }
#pragma unroll
    for (int r = 0; r < 4; ++r)
      atomicAdd(&U[b * 1024 + (wn * 16 + quad * 4 + r) * 32 + wm * 16 + l15], cx[r]);
  }
  // ph4b: partial spatial exp-sums S[e]
  {
    int d = t >> 3, j = t & 7;
    float s = 0.f;
#pragma unroll
    for (int q = 0; q < 8; ++q) s += __expf(kvb[d * 65 + j * 8 + q]);
#pragma unroll
    for (int off = 1; off <= 4; off <<= 1) s += __shfl_xor(s, off);
    if (j == 0) atomicAdd(&S[b * 32 + d], s);
  }
}

// ============================================================================
// KB: per 64-position tile:
//   stage ctxs = U/S; GEMM1 q = XTF x WqF with 4-DEEP A-fragment ring
//   (XTF is L3-resident ~600cy; 1-deep prefetch left ~400cy/kc exposed —
//   the round-8 47us stall) + W double-buffer (L2-hot); kc loop FULLY
//   unrolled so ring indices are compile-time (no scratch);
//   softmax in registers -> probs LDS; attended; ReLU; GEMM2 -> out.
// ============================================================================
__global__ __launch_bounds__(256, 3) void kb_mega(
    const f16* __restrict__ XTF, const f16* __restrict__ WqF, const float* __restrict__ bq1,
    const float* __restrict__ U, const float* __restrict__ S,
    const f16* __restrict__ WpF, const float* __restrict__ bp1,
    float* __restrict__ out) {
  __shared__ alignas(16) f16 pa[64 * 260];     // probs, then attended
  __shared__ alignas(16) f16 ctxs[32 * 36];    // ctx_t [d][e] pitch 36
  const int t = threadIdx.x, b = blockIdx.y, n0 = blockIdx.x * 64;
  const int lane = t & 63, w = t >> 6, l15 = lane & 15, quad = lane >> 4;
  const int wn = w & 1, wm = w >> 1;   // GEMM1: wn = o-half(128), wm = n-half(32)

  // issue the first half of the A-ring as early as possible (L3 latency)
  const f16* XF = XTF + ((size_t)b * 64 + blockIdx.x) * 16384;
  const f16* xb = XF + ((size_t)(wm * 2) * 64 + lane) * 8;      // + kc*2048 + mf*512
  f16x8 va0[4], va1[4];
#pragma unroll
  for (int p = 0; p < 4; ++p) {
    va0[p] = *(const f16x8*)&xb[p * 2048];
    va1[p] = *(const f16x8*)&xb[p * 2048 + 512];
  }

  // stage ctx = U/S (f32 -> f16, e-contiguous rows); ready by barrier #1
  {
    const float4 u4 = *(const float4*)&U[b * 1024 + t * 4];
    int d = t >> 3, e4 = (t & 7) * 4;
    const float4 s4 = *(const float4*)&S[b * 32 + e4];
    f16x4 pk = {(f16)(u4.x / s4.x), (f16)(u4.y / s4.y),
                (f16)(u4.z / s4.z), (f16)(u4.w / s4.w)};
    *(f16x4*)&ctxs[d * 36 + e4] = pk;
  }

  // ---------------- GEMM1: D1[n 64][o 256] ----------------
  f32x4 acc1[2][8];
#pragma unroll
  for (int nf = 0; nf < 8; ++nf) {
    float bv = bq1[wn * 128 + nf * 16 + l15];
#pragma unroll
    for (int mf = 0; mf < 2; ++mf)
#pragma unroll
      for (int r = 0; r < 4; ++r) acc1[mf][nf][r] = bv;
  }
  {
    const f16* wb = WqF + ((size_t)(wn * 8) * 64 + lane) * 8;   // + kc*8192 + nf*512
    f16x8 vw[8];
#pragma unroll
    for (int nf = 0; nf < 8; ++nf) vw[nf] = *(const f16x8*)&wb[nf * 512];
#pragma unroll
    for (int kc = 0; kc < 8; ++kc) {           // FULL unroll: static ring indices
      f16x8 a0 = va0[kc & 3], a1 = va1[kc & 3];
      if (kc < 4) {                            // refill ring slot 4 ahead
        va0[kc & 3] = *(const f16x8*)&xb[(kc + 4) * 2048];
        va1[kc & 3] = *(const f16x8*)&xb[(kc + 4) * 2048 + 512];
      }
      f16x8 nw[8];
      if (kc < 7) {
        const f16* wb2 = wb + (size_t)(kc + 1) * 8192;
#pragma unroll
        for (int nf = 0; nf < 8; ++nf) nw[nf] = *(const f16x8*)&wb2[nf * 512];
      }
      __builtin_amdgcn_s_setprio(1);
#pragma unroll
      for (int nf = 0; nf < 8; ++nf) {
        acc1[0][nf] = MFMA16(a0, vw[nf], acc1[0][nf]);
        acc1[1][nf] = MFMA16(a1, vw[nf], acc1[1][nf]);
      }
      __builtin_amdgcn_s_setprio(0);
#pragma unroll
      for (int nf = 0; nf < 8; ++nf) vw[nf] = nw[nf];
    }
  }

  // ---------------- softmax over e per head (in-wave, l15 shuffles) --------
#pragma unroll
  for (int mf = 0; mf < 2; ++mf)
#pragma unroll
    for (int h = 0; h < 4; ++h) {
      f32x4 v0 = acc1[mf][h * 2], v1 = acc1[mf][h * 2 + 1];
      f32x4 mx;
#pragma unroll
      for (int r = 0; r < 4; ++r) mx[r] = fmaxf(v0[r], v1[r]);
#pragma unroll
      for (int off = 1; off <= 8; off <<= 1)
#pragma unroll
        for (int r = 0; r < 4; ++r) mx[r] = fmaxf(mx[r], __shfl_xor(mx[r], off));
      f32x4 s4;
#pragma unroll
      for (int r = 0; r < 4; ++r) {
        v0[r] = __expf(v0[r] - mx[r]); v1[r] = __expf(v1[r] - mx[r]);
        s4[r] = v0[r] + v1[r];
      }
#pragma unroll
      for (int off = 1; off <= 8; off <<= 1)
#pragma unroll
        for (int r = 0; r < 4; ++r) s4[r] += __shfl_xor(s4[r], off);
      int o0 = wn * 128 + h * 32 + l15;
#pragma unroll
      for (int r = 0; r < 4; ++r) {
        int n = wm * 32 + mf * 16 + quad * 4 + r;
        float si = 1.f / s4[r];
        pa[n * 260 + o0]      = (f16)(v0[r] * si);
        pa[n * 260 + o0 + 16] = (f16)(v1[r] * si);
      }
    }
  __syncthreads();   // barrier #1: probs + ctxs visible

  // ---------------- attended = ctx_t * probs per head; ReLU in-place -------
  // wave w touches only columns [64w, 64w+64) of pa -> no cross-wave race
  f32x4 datt[2][2][4] = {};   // [head-local][d-half][n-frag]
#pragma unroll
  for (int hh = 0; hh < 2; ++hh) {
    int h = w * 2 + hh;
#pragma unroll
    for (int mt = 0; mt < 2; ++mt) {
      f16x8 af = ld8(&ctxs[(mt * 16 + l15) * 36 + quad * 8]);
      __builtin_amdgcn_s_setprio(1);
#pragma unroll
      for (int nt = 0; nt < 4; ++nt) {
        f16x8 bf = ld8(&pa[(nt * 16 + l15) * 260 + h * 32 + quad * 8]);
        datt[hh][mt][nt] = MFMA16(af, bf, datt[hh][mt][nt]);
      }
      __builtin_amdgcn_s_setprio(0);
    }
  }
#pragma unroll
  for (int hh = 0; hh < 2; ++hh) {
    int h = w * 2 + hh;
#pragma unroll
    for (int mt = 0; mt < 2; ++mt)
#pragma unroll
      for (int nt = 0; nt < 4; ++nt)
#pragma unroll
        for (int r = 0; r < 4; ++r) {
          int n = nt * 16 + l15;
          int cc = h * 32 + mt * 16 + quad * 4 + r;
          pa[n * 260 + cc] = (f16)fmaxf(datt[hh][mt][nt][r], 0.f);
        }
  }
  __syncthreads();   // barrier #2: attended visible

  // ---------------- GEMM2: out[o2 256][n 64], Wp frag-major 8-deep prefetch
  f32x4 acc2[8][2];
#pragma unroll
  for (int mf = 0; mf < 8; ++mf)
#pragma unroll
    for (int r = 0; r < 4; ++r) {
      float bv = bp1[wm * 128 + mf * 16 + quad * 4 + r];
      acc2[mf][0][r] = bv; acc2[mf][1][r] = bv;
    }
  {
    const f16* wb = WpF + ((size_t)(wm * 8) * 64 + lane) * 8;   // + kc*8192 + mf*512
    f16x8 vw[8];
#pragma unroll
    for (int mf = 0; mf < 8; ++mf) vw[mf] = *(const f16x8*)&wb[mf * 512];
#pragma unroll 1
    for (int kc = 0; kc < 8; ++kc) {
      f16x8 nw[8];
      if (kc < 7) {
        const f16* wb2 = wb + (size_t)(kc + 1) * 8192;
#pragma unroll
        for (int mf = 0; mf < 8; ++mf) nw[mf] = *(const f16x8*)&wb2[mf * 512];
      }
      f16x8 bf0 = ld8(&pa[(wn * 32 + l15) * 260 + kc * 32 + quad * 8]);
      f16x8 bf1 = ld8(&pa[(wn * 32 + 16 + l15) * 260 + kc * 32 + quad * 8]);
      __builtin_amdgcn_s_setprio(1);
#pragma unroll
      for (int mf = 0; mf < 8; ++mf) {
        acc2[mf][0] = MFMA16(vw[mf], bf0, acc2[mf][0]);
        acc2[mf][1] = MFMA16(vw[mf], bf1, acc2[mf][1]);
      }
      __builtin_amdgcn_s_setprio(0);
#pragma unroll
      for (int mf = 0; mf < 8; ++mf) vw[mf] = nw[mf];
    }
  }
#pragma unroll
  for (int mf = 0; mf < 8; ++mf)
#pragma unroll
    for (int nf = 0; nf < 2; ++nf) {
      int n = n0 + wn * 32 + nf * 16 + l15;
#pragma unroll
      for (int r = 0; r < 4; ++r) {
        int o = wm * 128 + mf * 16 + quad * 4 + r;
        out[((size_t)b * C + o) * HW + n] = acc2[mf][nf][r];
      }
    }
}

// ============================================================================
extern "C" void kernel_launch(void* const* d_in, const int* in_sizes, int n_in,
                              void* d_out, int out_size, void* d_ws, size_t ws_size,
                              hipStream_t stream) {
  (void)in_sizes; (void)n_in; (void)out_size; (void)ws_size;
  const float* input = (const float*)d_in[0];
  const float* Wq  = (const float*)d_in[2];
  const float* gq  = (const float*)d_in[3];
  const float* bq  = (const float*)d_in[4];
  const float* mq  = (const float*)d_in[5];
  const float* vq  = (const float*)d_in[6];
  const float* Wkv = (const float*)d_in[7];
  const float* gkv = (const float*)d_in[8];
  const float* bkv = (const float*)d_in[9];
  const float* mkv = (const float*)d_in[10];
  const float* vkv = (const float*)d_in[11];
  const float* Wp  = (const float*)d_in[12];
  const float* gp  = (const float*)d_in[13];
  const float* bp  = (const float*)d_in[14];
  const float* mp  = (const float*)d_in[15];
  const float* vp  = (const float*)d_in[16];

  char* ws = (char*)d_ws;
  f16*   XTF = (f16*)(ws + OFF_XT);
  f16*   WqF = (f16*)(ws + OFF_W1);
  f16*   WkvF= (f16*)(ws + OFF_W1 + 131072);
  float* b1  = (float*)(ws + OFF_B1);
  f16*   WpF = (f16*)(ws + OFF_WP);
  float* bp2 = (float*)(ws + OFF_BP);
  float* U   = (float*)(ws + OFF_U);
  float* S   = (float*)(ws + OFF_S);
  float* out = (float*)d_out;

  const float* bq1  = b1;
  const float* bkv1 = b1 + 256;

  k0_prep<<<613, 256, 0, stream>>>(Wq, gq, bq, mq, vq, Wkv, gkv, bkv, mkv, vkv,
                                   Wp, gp, bp, mp, vp, WqF, b1, WpF, bp2, WkvF, U, S);
  ka_trans_kv<<<dim3(64, 16), 256, 0, stream>>>(input, WkvF, bkv1, XTF, U, S);
  kb_mega<<<dim3(64, 16), 256, 0, stream>>>(XTF, WqF, bq1, U, S, WpF, bp2, out);
}

// Round 10
// 195.095 us; speedup vs baseline: 1.0363x; 1.0363x over previous
//
#include <hip/hip_runtime.h>
#include <hip/hip_bf16.h>
#include <cstdint>

typedef _Float16 f16;
typedef _Float16 f16x4 __attribute__((ext_vector_type(4)));
typedef _Float16 f16x8 __attribute__((ext_vector_type(8)));
typedef float f32x4 __attribute__((ext_vector_type(4)));

#define MFMA16(a, b, c) __builtin_amdgcn_mfma_f32_16x16x32_f16((a), (b), (c), 0, 0, 0)

constexpr int BATCH = 16;
constexpr int C     = 256;    // dim
constexpr int HW    = 4096;   // 64*64 spatial
constexpr int DH    = 32;     // qkv_dim
constexpr float EPS = 1e-5f;

// ---- workspace layout (bytes) ----
constexpr size_t OFF_XT = 0;                                   // XTF frag-major f16 [16][64tile][32KB]
constexpr size_t SZ_XT  = (size_t)BATCH * HW * C * 2;          // 32 MB
constexpr size_t OFF_W1 = OFF_XT + SZ_XT;                      // WqF (131072 B) + WkvF (16384 B)
constexpr size_t OFF_B1 = OFF_W1 + 147456;                     // f32 [288]
constexpr size_t OFF_WP = OFF_B1 + 2048;                       // WpF frag-major
constexpr size_t SZ_WP  = (size_t)C * C * 2;
constexpr size_t OFF_BP = OFF_WP + SZ_WP;                      // f32 [256]
constexpr size_t OFF_U  = OFF_BP + 1024;                       // f32 [16][32][32] (unnormalized ctx)
constexpr size_t OFF_S  = OFF_U + 65536;                       // f32 [16][32] spatial exp-sums

__device__ __forceinline__ f16x8 ld8(const f16* p) {           // 8B-aligned LDS load
  f16x4 lo = *(const f16x4*)p;
  f16x4 hi = *(const f16x4*)(p + 4);
  return __builtin_shufflevector(lo, hi, 0, 1, 2, 3, 4, 5, 6, 7);
}

// async global->LDS, 16B per lane; LDS dest = wave-uniform base + lane*16 (HW)
__device__ __forceinline__ void gload_lds16(const f16* g, f16* l) {
  __builtin_amdgcn_global_load_lds(
      (const __attribute__((address_space(1))) void*)g,
      (__attribute__((address_space(3))) void*)l, 16, 0, 0);
}

// ============================================================================
// K0: fold BN into conv weights (FRAGMENT-MAJOR f16) + zero U/S accumulators.
// Frag layout: idx = ((kc*NT + ot)*64 + lane)*8 + j holds
//   W[o = ot*16 + (lane&15)][c = kc*32 + (lane>>4)*8 + j]
// ============================================================================
__global__ __launch_bounds__(256) void k0_prep(
    const float* __restrict__ Wq,  const float* __restrict__ gq,  const float* __restrict__ bq,
    const float* __restrict__ mq,  const float* __restrict__ vq,
    const float* __restrict__ Wkv, const float* __restrict__ gkv, const float* __restrict__ bkv,
    const float* __restrict__ mkv, const float* __restrict__ vkv,
    const float* __restrict__ Wp,  const float* __restrict__ gp,  const float* __restrict__ bp,
    const float* __restrict__ mp,  const float* __restrict__ vp,
    f16* __restrict__ WqF, float* __restrict__ b1, f16* __restrict__ WpF,
    float* __restrict__ bp2, f16* __restrict__ WkvF, float* __restrict__ U,
    float* __restrict__ S) {
  int id = blockIdx.x * 256 + threadIdx.x;
  if (id < 65536) {
    int j = id & 7, lane = (id >> 3) & 63, ot = (id >> 9) & 15, kc = id >> 13;
    int o = ot * 16 + (lane & 15), c = kc * 32 + ((lane >> 4) << 3) + j;
    float inv = gq[o] * rsqrtf(vq[o] + EPS);
    WqF[id] = (f16)(Wq[o * 256 + c] * inv);
  } else if (id < 131072) {
    int id2 = id - 65536;
    int j = id2 & 7, lane = (id2 >> 3) & 63, ot = (id2 >> 9) & 15, kc = id2 >> 13;
    int o = ot * 16 + (lane & 15), c = kc * 32 + ((lane >> 4) << 3) + j;
    float inv = gp[o] * rsqrtf(vp[o] + EPS);
    WpF[id2] = (f16)(Wp[o * 256 + c] * inv);
  } else if (id < 139264) {
    int id2 = id - 131072;
    int j = id2 & 7, lane = (id2 >> 3) & 63, ot = (id2 >> 9) & 1, kc = id2 >> 10;
    int o = ot * 16 + (lane & 15), c = kc * 32 + ((lane >> 4) << 3) + j;
    float inv = gkv[o] * rsqrtf(vkv[o] + EPS);
    WkvF[id2] = (f16)(Wkv[o * 256 + c] * inv);
  } else if (id < 139552) {
    int r = id - 139264;
    if (r < 256) { float inv = gq[r] * rsqrtf(vq[r] + EPS);   b1[r] = bq[r] - mq[r] * inv; }
    else { int e = r - 256; float inv = gkv[e] * rsqrtf(vkv[e] + EPS); b1[r] = bkv[e] - mkv[e] * inv; }
  } else if (id < 139808) {
    int o = id - 139552;
    float inv = gp[o] * rsqrtf(vp[o] + EPS);
    bp2[o] = bp[o] - mp[o] * inv;
  } else if (id < 156192) {
    U[id - 139808] = 0.f;
  } else if (id < 156704) {
    S[id - 156192] = 0.f;
  }
}

// ============================================================================
// KA: per 64-position tile (small register footprint, (256,4)):
//   ph1: ALL 16 X-loads batched into registers (max MLP), 4x4 register
//        transpose f32->f16 -> xt LDS [n][c]
//   ph2: XTF frag-major stores + kv-GEMM (WkvF frag-major, L1-hot)
//   ph3: kv accs -> kvb LDS (aliases xt, pitch 65 conflict-free)
//   ph4: partial ctx U[d][e] += kv.exp(kv)^T via MFMA + atomics;
//        S[e] += sum exp(kv)  (kv bounded so exp is max-free)
// ============================================================================
__global__ __launch_bounds__(256, 4) void ka_trans_kv(
    const float* __restrict__ X, const f16* __restrict__ WkvF, const float* __restrict__ bkv1,
    f16* __restrict__ XTF, float* __restrict__ U, float* __restrict__ S) {
  __shared__ alignas(16) f16 xt[64 * 260];     // [n][c] pitch 260; reused as kvb
  float* kvb = (float*)xt;                     // [d][n] pitch 65 (8320 B)
  const int t = threadIdx.x, b = blockIdx.y, n0 = blockIdx.x * 64;
  const int lane = t & 63, w = t >> 6, l15 = lane & 15, quad = lane >> 4;
  const int wn = w & 1, wm = w >> 1;
  const float* Xb = X + (size_t)b * C * HW;

  // ph1: batch-issue all 16 global loads, then transpose f32->f16 into LDS
  {
    int n4 = (t & 15) * 4, c4 = (t >> 4) * 4;
    float4 vb[4][4];
#pragma unroll
    for (int ci = 0; ci < 4; ++ci) {
      const float* xp = Xb + (size_t)(ci * 64 + c4) * HW + n0 + n4;
      vb[ci][0] = *(const float4*)&xp[0];
      vb[ci][1] = *(const float4*)&xp[HW];
      vb[ci][2] = *(const float4*)&xp[2 * HW];
      vb[ci][3] = *(const float4*)&xp[3 * HW];
    }
#pragma unroll
    for (int ci = 0; ci < 4; ++ci) {
      int c0 = ci * 64 + c4;
      float4 v0 = vb[ci][0], v1 = vb[ci][1], v2 = vb[ci][2], v3 = vb[ci][3];
      f16x4 w0 = {(f16)v0.x, (f16)v1.x, (f16)v2.x, (f16)v3.x};
      f16x4 w1 = {(f16)v0.y, (f16)v1.y, (f16)v2.y, (f16)v3.y};
      f16x4 w2 = {(f16)v0.z, (f16)v1.z, (f16)v2.z, (f16)v3.z};
      f16x4 w3 = {(f16)v0.w, (f16)v1.w, (f16)v2.w, (f16)v3.w};
      *(f16x4*)&xt[(n4 + 0) * 260 + c0] = w0;
      *(f16x4*)&xt[(n4 + 1) * 260 + c0] = w1;
      *(f16x4*)&xt[(n4 + 2) * 260 + c0] = w2;
      *(f16x4*)&xt[(n4 + 3) * 260 + c0] = w3;
    }
  }
  __syncthreads();   // sync A

  // ph2a: XTF fragment-major stores (consecutive 16B per thread, coalesced)
  {
    f16* XFt = XTF + ((size_t)b * 64 + blockIdx.x) * 16384;
#pragma unroll
    for (int i = 0; i < 8; ++i) {
      int u = t + i * 256;                     // (kc,nt,lane) linear
      int l15u = u & 15, qdu = (u >> 4) & 3, ntu = (u >> 6) & 3, kcu = u >> 8;
      f16x8 v = ld8(&xt[(ntu * 16 + l15u) * 260 + kcu * 32 + qdu * 8]);
      *(f16x8*)&XFt[(size_t)u * 8] = v;
    }
  }

  // ph2b: kv GEMM. A = xt rows (wave w owns n rows w*16..+15),
  // B-frags frag-major from WkvF (16KB, L1-hot). Bias in acc init.
  f32x4 acc0, acc1;
  {
    float bv0 = bkv1[l15], bv1 = bkv1[16 + l15];
#pragma unroll
    for (int r = 0; r < 4; ++r) { acc0[r] = bv0; acc1[r] = bv1; }
  }
#pragma unroll
  for (int kc = 0; kc < 8; ++kc) {
    f16x8 af  = ld8(&xt[(w * 16 + l15) * 260 + kc * 32 + quad * 8]);
    f16x8 bf0 = *(const f16x8*)&WkvF[((size_t)(kc * 2 + 0) * 64 + lane) * 8];
    f16x8 bf1 = *(const f16x8*)&WkvF[((size_t)(kc * 2 + 1) * 64 + lane) * 8];
    acc0 = MFMA16(af, bf0, acc0);
    acc1 = MFMA16(af, bf1, acc1);
  }
  __syncthreads();   // sync B: all xt reads done -> safe to alias as kvb

  // ph3: kv accs -> kvb [d][n] pitch 65
#pragma unroll
  for (int r = 0; r < 4; ++r) {
    int n = w * 16 + quad * 4 + r;
    kvb[l15 * 65 + n] = acc0[r];
    kvb[(16 + l15) * 65 + n] = acc1[r];
  }
  __syncthreads();   // sync C

  // ph4a: partial ctx via MFMA; wave -> quadrant (dh=wn, eh=wm)
  {
    f32x4 cx = {0.f, 0.f, 0.f, 0.f};
#pragma unroll
    for (int ks = 0; ks < 2; ++ks) {
      f16x8 A, B;
#pragma unroll
      for (int j = 0; j < 8; ++j) {
        float av = kvb[(wn * 16 + l15) * 65 + ks * 32 + quad * 8 + j];
        float bv = kvb[(wm * 16 + l15) * 65 + ks * 32 + quad * 8 + j];
        A[j] = (f16)av;
        B[j] = (f16)__expf(bv);
      }
      cx = MFMA16(A, B, cx);
    }
#pragma unroll
    for (int r = 0; r < 4; ++r)
      atomicAdd(&U[b * 1024 + (wn * 16 + quad * 4 + r) * 32 + wm * 16 + l15], cx[r]);
  }
  // ph4b: partial spatial exp-sums S[e]
  {
    int d = t >> 3, j = t & 7;
    float s = 0.f;
#pragma unroll
    for (int q = 0; q < 8; ++q) s += __expf(kvb[d * 65 + j * 8 + q]);
#pragma unroll
    for (int off = 1; off <= 4; off <<= 1) s += __shfl_xor(s, off);
    if (j == 0) atomicAdd(&S[b * 32 + d], s);
  }
}

// ============================================================================
// KB: per 64-position tile:
//   entry: async-stage the 32KB XTF tile into LDS via global_load_lds
//     (ZERO VGPR cost — r9's register-ring spilled; this is the fix) while
//     ctx staging hides the L3 latency; barrier drains vmcnt.
//   GEMM1: A-frags via conflict-free ds_read_b128 from LDS, W register-dbuf
//     (L2-hot); softmax in regs; barrier; probs -> pa (aliases xtile);
//   attended; ReLU; GEMM2 (Wp frag-major 8-deep) -> out.
// ============================================================================
__global__ __launch_bounds__(256, 3) void kb_mega(
    const f16* __restrict__ XTF, const f16* __restrict__ WqF, const float* __restrict__ bq1,
    const float* __restrict__ U, const float* __restrict__ S,
    const f16* __restrict__ WpF, const float* __restrict__ bp1,
    float* __restrict__ out) {
  __shared__ alignas(16) f16 pa[64 * 260];     // xtile (32KB), then probs/attended
  __shared__ alignas(16) f16 ctxs[32 * 36];    // ctx_t [d][e] pitch 36
  const int t = threadIdx.x, b = blockIdx.y, n0 = blockIdx.x * 64;
  const int lane = t & 63, w = t >> 6, l15 = lane & 15, quad = lane >> 4;
  const int wn = w & 1, wm = w >> 1;   // GEMM1: wn = o-half(128), wm = n-half(32)

  // async-stage XTF tile -> LDS (linear, mirrors frag-major global layout).
  // iter i, thread t: global 16B at u=t+i*256; LDS dest uniform base
  // (w*1024 + i*4096 bytes) + lane*16 (added by HW).
  {
    const f16* XFt = XTF + ((size_t)b * 64 + blockIdx.x) * 16384;
#pragma unroll
    for (int i = 0; i < 8; ++i)
      gload_lds16(XFt + ((size_t)t + i * 256) * 8, &pa[w * 512 + i * 2048]);
  }

  // stage ctx = U/S (f32 -> f16, e-contiguous rows) — hides xtile latency
  {
    const float4 u4 = *(const float4*)&U[b * 1024 + t * 4];
    int d = t >> 3, e4 = (t & 7) * 4;
    const float4 s4 = *(const float4*)&S[b * 32 + e4];
    f16x4 pk = {(f16)(u4.x / s4.x), (f16)(u4.y / s4.y),
                (f16)(u4.z / s4.z), (f16)(u4.w / s4.w)};
    *(f16x4*)&ctxs[d * 36 + e4] = pk;
  }
  __syncthreads();   // barrier S: vmcnt drained -> xtile + ctxs ready

  // ---------------- GEMM1: D1[n 64][o 256]; A from LDS, W reg-dbuf ---------
  f32x4 acc1[2][8];
#pragma unroll
  for (int nf = 0; nf < 8; ++nf) {
    float bv = bq1[wn * 128 + nf * 16 + l15];
#pragma unroll
    for (int mf = 0; mf < 2; ++mf)
#pragma unroll
      for (int r = 0; r < 4; ++r) acc1[mf][nf][r] = bv;
  }
  {
    const f16* wb = WqF + ((size_t)(wn * 8) * 64 + lane) * 8;   // + kc*8192 + nf*512
    f16x8 vw[8];
#pragma unroll
    for (int nf = 0; nf < 8; ++nf) vw[nf] = *(const f16x8*)&wb[nf * 512];
#pragma unroll 1
    for (int kc = 0; kc < 8; ++kc) {
      f16x8 nw[8];
      if (kc < 7) {
        const f16* wb2 = wb + (size_t)(kc + 1) * 8192;
#pragma unroll
        for (int nf = 0; nf < 8; ++nf) nw[nf] = *(const f16x8*)&wb2[nf * 512];
      }
      // A-frags: consecutive 16B per lane -> conflict-free ds_read_b128
      f16x8 a0 = *(const f16x8*)&pa[((kc * 4 + wm * 2 + 0) * 64 + lane) * 8];
      f16x8 a1 = *(const f16x8*)&pa[((kc * 4 + wm * 2 + 1) * 64 + lane) * 8];
      __builtin_amdgcn_s_setprio(1);
#pragma unroll
      for (int nf = 0; nf < 8; ++nf) {
        acc1[0][nf] = MFMA16(a0, vw[nf], acc1[0][nf]);
        acc1[1][nf] = MFMA16(a1, vw[nf], acc1[1][nf]);
      }
      __builtin_amdgcn_s_setprio(0);
#pragma unroll
      for (int nf = 0; nf < 8; ++nf) vw[nf] = nw[nf];
    }
  }
  __syncthreads();   // barrier T: all xtile reads done -> pa reusable as probs

  // ---------------- softmax over e per head (in-wave, l15 shuffles) --------
#pragma unroll
  for (int mf = 0; mf < 2; ++mf)
#pragma unroll
    for (int h = 0; h < 4; ++h) {
      f32x4 v0 = acc1[mf][h * 2], v1 = acc1[mf][h * 2 + 1];
      f32x4 mx;
#pragma unroll
      for (int r = 0; r < 4; ++r) mx[r] = fmaxf(v0[r], v1[r]);
#pragma unroll
      for (int off = 1; off <= 8; off <<= 1)
#pragma unroll
        for (int r = 0; r < 4; ++r) mx[r] = fmaxf(mx[r], __shfl_xor(mx[r], off));
      f32x4 s4;
#pragma unroll
      for (int r = 0; r < 4; ++r) {
        v0[r] = __expf(v0[r] - mx[r]); v1[r] = __expf(v1[r] - mx[r]);
        s4[r] = v0[r] + v1[r];
      }
#pragma unroll
      for (int off = 1; off <= 8; off <<= 1)
#pragma unroll
        for (int r = 0; r < 4; ++r) s4[r] += __shfl_xor(s4[r], off);
      int o0 = wn * 128 + h * 32 + l15;
#pragma unroll
      for (int r = 0; r < 4; ++r) {
        int n = wm * 32 + mf * 16 + quad * 4 + r;
        float si = 1.f / s4[r];
        pa[n * 260 + o0]      = (f16)(v0[r] * si);
        pa[n * 260 + o0 + 16] = (f16)(v1[r] * si);
      }
    }
  __syncthreads();   // barrier #1: probs visible

  // ---------------- attended = ctx_t * probs per head; ReLU in-place -------
  // wave w touches only columns [64w, 64w+64) of pa -> no cross-wave race
  f32x4 datt[2][2][4] = {};   // [head-local][d-half][n-frag]
#pragma unroll
  for (int hh = 0; hh < 2; ++hh) {
    int h = w * 2 + hh;
#pragma unroll
    for (int mt = 0; mt < 2; ++mt) {
      f16x8 af = ld8(&ctxs[(mt * 16 + l15) * 36 + quad * 8]);
      __builtin_amdgcn_s_setprio(1);
#pragma unroll
      for (int nt = 0; nt < 4; ++nt) {
        f16x8 bf = ld8(&pa[(nt * 16 + l15) * 260 + h * 32 + quad * 8]);
        datt[hh][mt][nt] = MFMA16(af, bf, datt[hh][mt][nt]);
      }
      __builtin_amdgcn_s_setprio(0);
    }
  }
#pragma unroll
  for (int hh = 0; hh < 2; ++hh) {
    int h = w * 2 + hh;
#pragma unroll
    for (int mt = 0; mt < 2; ++mt)
#pragma unroll
      for (int nt = 0; nt < 4; ++nt)
#pragma unroll
        for (int r = 0; r < 4; ++r) {
          int n = nt * 16 + l15;
          int cc = h * 32 + mt * 16 + quad * 4 + r;
          pa[n * 260 + cc] = (f16)fmaxf(datt[hh][mt][nt][r], 0.f);
        }
  }
  __syncthreads();   // barrier #2: attended visible

  // ---------------- GEMM2: out[o2 256][n 64], Wp frag-major 8-deep prefetch
  f32x4 acc2[8][2];
#pragma unroll
  for (int mf = 0; mf < 8; ++mf)
#pragma unroll
    for (int r = 0; r < 4; ++r) {
      float bv = bp1[wm * 128 + mf * 16 + quad * 4 + r];
      acc2[mf][0][r] = bv; acc2[mf][1][r] = bv;
    }
  {
    const f16* wb = WpF + ((size_t)(wm * 8) * 64 + lane) * 8;   // + kc*8192 + mf*512
    f16x8 vw[8];
#pragma unroll
    for (int mf = 0; mf < 8; ++mf) vw[mf] = *(const f16x8*)&wb[mf * 512];
#pragma unroll 1
    for (int kc = 0; kc < 8; ++kc) {
      f16x8 nw[8];
      if (kc < 7) {
        const f16* wb2 = wb + (size_t)(kc + 1) * 8192;
#pragma unroll
        for (int mf = 0; mf < 8; ++mf) nw[mf] = *(const f16x8*)&wb2[mf * 512];
      }
      f16x8 bf0 = ld8(&pa[(wn * 32 + l15) * 260 + kc * 32 + quad * 8]);
      f16x8 bf1 = ld8(&pa[(wn * 32 + 16 + l15) * 260 + kc * 32 + quad * 8]);
      __builtin_amdgcn_s_setprio(1);
#pragma unroll
      for (int mf = 0; mf < 8; ++mf) {
        acc2[mf][0] = MFMA16(vw[mf], bf0, acc2[mf][0]);
        acc2[mf][1] = MFMA16(vw[mf], bf1, acc2[mf][1]);
      }
      __builtin_amdgcn_s_setprio(0);
#pragma unroll
      for (int mf = 0; mf < 8; ++mf) vw[mf] = nw[mf];
    }
  }
#pragma unroll
  for (int mf = 0; mf < 8; ++mf)
#pragma unroll
    for (int nf = 0; nf < 2; ++nf) {
      int n = n0 + wn * 32 + nf * 16 + l15;
#pragma unroll
      for (int r = 0; r < 4; ++r) {
        int o = wm * 128 + mf * 16 + quad * 4 + r;
        out[((size_t)b * C + o) * HW + n] = acc2[mf][nf][r];
      }
    }
}

// ============================================================================
extern "C" void kernel_launch(void* const* d_in, const int* in_sizes, int n_in,
                              void* d_out, int out_size, void* d_ws, size_t ws_size,
                              hipStream_t stream) {
  (void)in_sizes; (void)n_in; (void)out_size; (void)ws_size;
  const float* input = (const float*)d_in[0];
  const float* Wq  = (const float*)d_in[2];
  const float* gq  = (const float*)d_in[3];
  const float* bq  = (const float*)d_in[4];
  const float* mq  = (const float*)d_in[5];
  const float* vq  = (const float*)d_in[6];
  const float* Wkv = (const float*)d_in[7];
  const float* gkv = (const float*)d_in[8];
  const float* bkv = (const float*)d_in[9];
  const float* mkv = (const float*)d_in[10];
  const float* vkv = (const float*)d_in[11];
  const float* Wp  = (const float*)d_in[12];
  const float* gp  = (const float*)d_in[13];
  const float* bp  = (const float*)d_in[14];
  const float* mp  = (const float*)d_in[15];
  const float* vp  = (const float*)d_in[16];

  char* ws = (char*)d_ws;
  f16*   XTF = (f16*)(ws + OFF_XT);
  f16*   WqF = (f16*)(ws + OFF_W1);
  f16*   WkvF= (f16*)(ws + OFF_W1 + 131072);
  float* b1  = (float*)(ws + OFF_B1);
  f16*   WpF = (f16*)(ws + OFF_WP);
  float* bp2 = (float*)(ws + OFF_BP);
  float* U   = (float*)(ws + OFF_U);
  float* S   = (float*)(ws + OFF_S);
  float* out = (float*)d_out;

  const float* bq1  = b1;
  const float* bkv1 = b1 + 256;

  k0_prep<<<613, 256, 0, stream>>>(Wq, gq, bq, mq, vq, Wkv, gkv, bkv, mkv, vkv,
                                   Wp, gp, bp, mp, vp, WqF, b1, WpF, bp2, WkvF, U, S);
  ka_trans_kv<<<dim3(64, 16), 256, 0, stream>>>(input, WkvF, bkv1, XTF, U, S);
  kb_mega<<<dim3(64, 16), 256, 0, stream>>>(XTF, WqF, bq1, U, S, WpF, bp2, out);
}